// Round 3
// baseline (2326.567 us; speedup 1.0000x reference)
//
#include <hip/hip_runtime.h>
#include <hip/hip_bf16.h>

#define CCH 128
#define HGT 256
#define WID 256
#define HW  65536

typedef __attribute__((ext_vector_type(8))) short short8;
typedef __attribute__((ext_vector_type(4))) float floatx4;

// ws layout:
//   floats [0,512)     sum_h (4*128)
//   floats [512,1024)  sum_v
//   floats [1024,1032) wgate (4*2)
//   float  [1032]      block-completion counter (int, zeroed by prep)
//   byte 32768:        hbuf bf16 (4*128*65536)
//   then               vbuf bf16

__device__ __forceinline__ float bf2f(unsigned short u) {
  return __uint_as_float(((unsigned)u) << 16);
}
__device__ __forceinline__ short f2bfs(float f) {
  return (short)__bfloat16_as_ushort(__float2bfloat16(f));
}

__global__ __launch_bounds__(256) void prep_kernel(float* __restrict__ sums) {
  int t = threadIdx.x;
  for (int i = t; i < 1040; i += 256) sums[i] = 0.f;  // sums, wgate, counter
}

// Merged directional conv + last-block gate. 12288 blocks: first 8192
// horizontal (16 rows x 256 px, 16 px/thread), rest vertical (32 rows x 256
// cols, 32 y/thread). Register-resident two-stage conv, no LDS in hot path.
// The LAST block to finish (threadfence + counter) computes the gate MLP with
// all 256 threads and writes wgate — removes the 1-block gate kernel launch.
__global__ __launch_bounds__(256) void conv_kernel(
    const float* __restrict__ x,
    const float* __restrict__ h1w, const float* __restrict__ h2w,
    const float* __restrict__ v1w, const float* __restrict__ v2w,
    const float* __restrict__ g1w, const float* __restrict__ g2w,
    const float* __restrict__ g2b,
    __hip_bfloat16* __restrict__ hbuf, __hip_bfloat16* __restrict__ vbuf,
    float* __restrict__ sums) {
  float* sum_h = sums;
  float* sum_v = sums + 512;
  float* wgate = sums + 1024;
  unsigned int* counter = (unsigned int*)(sums + 1032);

  int d = blockIdx.x;
  int l = (d & 7) * 1536 + (d >> 3);   // bijective XCD chunking: 12288 % 8 == 0
  int t = threadIdx.x;
  float acc = 0.f;
  int bcg;
  float* accdst;
  if (l < 8192) {
    // ---- horizontal: block = (b,c, 16-row tile); thread = 16 consecutive px
    int bc = l >> 4;
    int c = bc & (CCH - 1);
    int row = (l & 15) * 16 + (t >> 4);
    int p0 = (t & 15) * 16;
    const float* xr = x + (size_t)bc * HW + (size_t)row * WID;
    float w1[5], w2[7];
#pragma unroll
    for (int i = 0; i < 5; ++i) w1[i] = h1w[c * 5 + i];
#pragma unroll
    for (int j = 0; j < 7; ++j) w2[j] = h2w[c * 7 + j];
    float xv[40];
#pragma unroll
    for (int k = 0; k < 10; ++k) {
      int col = p0 - 12 + 4 * k;
      float4 v = make_float4(0.f, 0.f, 0.f, 0.f);
      if (col >= 0 && col < WID) v = *(const float4*)(xr + col);
      xv[4 * k] = v.x; xv[4 * k + 1] = v.y; xv[4 * k + 2] = v.z; xv[4 * k + 3] = v.w;
    }
    float s1[34];
#pragma unroll
    for (int m = 0; m < 34; ++m) {
      int q = p0 - 9 + m;
      float s = 0.f;
#pragma unroll
      for (int i = 0; i < 5; ++i) s = fmaf(xv[m + 1 + i], w1[i], s);
      s1[m] = ((unsigned)q < (unsigned)WID) ? s : 0.f;
    }
    short8 st0, st1;
#pragma unroll
    for (int u = 0; u < 16; ++u) {
      float s = 0.f;
#pragma unroll
      for (int j = 0; j < 7; ++j) s = fmaf(s1[u + 3 * j], w2[j], s);
      if (u < 8) st0[u] = f2bfs(s); else st1[u - 8] = f2bfs(s);
      acc += s;
    }
    unsigned short* hp = (unsigned short*)hbuf + (size_t)bc * HW + (size_t)row * WID + p0;
    *(short8*)hp = st0;
    *(short8*)(hp + 8) = st1;
    bcg = bc; accdst = sum_h;
  } else {
    // ---- vertical: block = (b,c, 32-row tile); thread = one column, 32 y's
    int lb = l - 8192;
    int bc = lb >> 3;
    int c = bc & (CCH - 1);
    int y0 = (lb & 7) * 32;
    const float* xc = x + (size_t)bc * HW + t;
    float w1[5], w2[7];
#pragma unroll
    for (int i = 0; i < 5; ++i) w1[i] = v1w[c * 5 + i];
#pragma unroll
    for (int j = 0; j < 7; ++j) w2[j] = v2w[c * 7 + j];
    float xv[54];
#pragma unroll
    for (int m = 0; m < 54; ++m) {
      int yy = y0 - 11 + m;
      xv[m] = ((unsigned)yy < (unsigned)HGT) ? xc[(size_t)yy * WID] : 0.f;
    }
    float s1[50];
#pragma unroll
    for (int m = 0; m < 50; ++m) {
      int q = y0 - 9 + m;
      float s = 0.f;
#pragma unroll
      for (int i = 0; i < 5; ++i) s = fmaf(xv[m + i], w1[i], s);
      s1[m] = ((unsigned)q < (unsigned)HGT) ? s : 0.f;
    }
    unsigned short* vp = (unsigned short*)vbuf + (size_t)bc * HW + t;
#pragma unroll
    for (int u = 0; u < 32; ++u) {
      float s = 0.f;
#pragma unroll
      for (int j = 0; j < 7; ++j) s = fmaf(s1[u + 3 * j], w2[j], s);
      vp[(size_t)(y0 + u) * WID] = (unsigned short)f2bfs(s);
      acc += s;
    }
    bcg = bc; accdst = sum_v;
  }
#pragma unroll
  for (int off = 32; off > 0; off >>= 1) acc += __shfl_down(acc, off);
  if ((t & 63) == 0) atomicAdd(&accdst[bcg], acc);

  // ---- last-block gate (canonical threadfence + counter pattern)
  __shared__ float gsp[8][32];
  __shared__ float gsv[4][32];
  __shared__ int islast;
  __threadfence();
  __syncthreads();
  if (t == 0) islast = (atomicAdd(counter, 1u) == 12287u) ? 1 : 0;
  __syncthreads();
  if (islast) {
    const float inv = 1.f / 65536.f;
    int r = t & 31, seg = t >> 5;
#pragma unroll 1
    for (int bb = 0; bb < 4; ++bb) {
      const float* pv = (seg < 4) ? (sum_h + bb * 128 + seg * 32)
                                  : (sum_v + bb * 128 + (seg - 4) * 32);
      const float* wr = g1w + r * 256 + seg * 32;
      float pp = 0.f;
#pragma unroll
      for (int kk = 0; kk < 32; ++kk) pp = fmaf(pv[kk] * inv, wr[kk], pp);
      gsp[seg][r] = pp;
      __syncthreads();
      if (t < 32) {
        float s = 0.f;
#pragma unroll
        for (int sg = 0; sg < 8; ++sg) s += gsp[sg][t];
        gsv[bb][t] = s * (1.f / (1.f + expf(-s)));
      }
      __syncthreads();
    }
    if (t < 4) {
      float t0 = g2b[0], t1 = g2b[1];
#pragma unroll
      for (int rr = 0; rr < 32; ++rr) {
        t0 = fmaf(gsv[t][rr], g2w[rr], t0);
        t1 = fmaf(gsv[t][rr], g2w[32 + rr], t1);
      }
      float mx = fmaxf(t0, t1);
      float e0 = expf(t0 - mx), e1 = expf(t1 - mx);
      float is = 1.f / (e0 + e1);
      wgate[t * 2 + 0] = e0 * is;
      wgate[t * 2 + 1] = e1 * is;
    }
  }
}

// MFMA fuse: one block per (b, y, half) = 128 o x 128 p, K = 128 c.
// v3: operand-swapped MFMA — D[p][o] = mfma(aT_frag, W_frag, acc). A/B lane
// layouts are symmetric, so wf data and LDS reads are identical to v0; but
// now each lane's 4 acc regs are 4 CONSECUTIVE PIXELS at fixed o, so the
// epilogue is 16 float4 x-loads + 16 float4 stores instead of 64 scalars.
__global__ __launch_bounds__(256, 4) void fuse_kernel(
    const float* __restrict__ x, const __hip_bfloat16* __restrict__ hbuf,
    const __hip_bfloat16* __restrict__ vbuf, const float* __restrict__ fuse_w,
    const float* __restrict__ fuse_b, const float* __restrict__ wgate,
    float* __restrict__ out) {
  __shared__ unsigned short aT[128 * 128];  // [p][c'] bf16, 32 KB
  int bid = blockIdx.x;        // (b*256 + y)*2 + half
  int half = bid & 1;
  int y = (bid >> 1) & 255;
  int b = bid >> 9;
  int t = threadIdx.x;
  int w = t >> 6, lane = t & 63;
  int quad = lane >> 4, n16 = lane & 15;
  float wh = wgate[b * 2], wv = wgate[b * 2 + 1];

  // W fragments (B-operand now): wave w covers o in [32w, 32w+32)
  short8 wf[2][4];
#pragma unroll
  for (int ni = 0; ni < 2; ++ni) {
    int o = (2 * w + ni) * 16 + n16;
#pragma unroll
    for (int kt = 0; kt < 4; ++kt) {
      const float* wp = fuse_w + o * 128 + kt * 32 + quad * 8;
      float4 f0 = *(const float4*)wp;
      float4 f1 = *(const float4*)(wp + 4);
      short8 s;
      s[0] = f2bfs(f0.x); s[1] = f2bfs(f0.y); s[2] = f2bfs(f0.z); s[3] = f2bfs(f0.w);
      s[4] = f2bfs(f1.x); s[5] = f2bfs(f1.y); s[6] = f2bfs(f1.z); s[7] = f2bfs(f1.w);
      wf[ni][kt] = s;
    }
  }

  // stage a = wh*h + wv*v into aT[p][c'], c' = (c + 8*((p>>3)&15)) & 127
  size_t base = (size_t)(b * CCH) * HW + (size_t)y * WID + half * 128;
  const unsigned short* hb = (const unsigned short*)hbuf;
  const unsigned short* vb = (const unsigned short*)vbuf;
  int cth = t >> 4;
  int p0 = (t & 15) * 8;
  int swz = 8 * (t & 15);      // 8*((p>>3)&15), constant over the thread's 8 p
#pragma unroll
  for (int cpass = 0; cpass < 8; ++cpass) {
    int c = cpass * 16 + cth;
    size_t gi = base + (size_t)c * HW + p0;
    short8 h8 = *(const short8*)(hb + gi);
    short8 v8 = *(const short8*)(vb + gi);
    int cpr = (c + swz) & 127;
    float a0 = fmaf(wh, bf2f((unsigned short)h8[0]), wv * bf2f((unsigned short)v8[0]));
    float a1 = fmaf(wh, bf2f((unsigned short)h8[1]), wv * bf2f((unsigned short)v8[1]));
    float a2 = fmaf(wh, bf2f((unsigned short)h8[2]), wv * bf2f((unsigned short)v8[2]));
    float a3 = fmaf(wh, bf2f((unsigned short)h8[3]), wv * bf2f((unsigned short)v8[3]));
    float a4 = fmaf(wh, bf2f((unsigned short)h8[4]), wv * bf2f((unsigned short)v8[4]));
    float a5 = fmaf(wh, bf2f((unsigned short)h8[5]), wv * bf2f((unsigned short)v8[5]));
    float a6 = fmaf(wh, bf2f((unsigned short)h8[6]), wv * bf2f((unsigned short)v8[6]));
    float a7 = fmaf(wh, bf2f((unsigned short)h8[7]), wv * bf2f((unsigned short)v8[7]));
    aT[(p0 + 0) * 128 + cpr] = (unsigned short)f2bfs(a0);
    aT[(p0 + 1) * 128 + cpr] = (unsigned short)f2bfs(a1);
    aT[(p0 + 2) * 128 + cpr] = (unsigned short)f2bfs(a2);
    aT[(p0 + 3) * 128 + cpr] = (unsigned short)f2bfs(a3);
    aT[(p0 + 4) * 128 + cpr] = (unsigned short)f2bfs(a4);
    aT[(p0 + 5) * 128 + cpr] = (unsigned short)f2bfs(a5);
    aT[(p0 + 6) * 128 + cpr] = (unsigned short)f2bfs(a6);
    aT[(p0 + 7) * 128 + cpr] = (unsigned short)f2bfs(a7);
  }
  __syncthreads();

  // MFMA: acc[mt][ni] = D[p-tile mt][o-tile 2w+ni]
  floatx4 acc[8][2];
#pragma unroll
  for (int mt = 0; mt < 8; ++mt)
#pragma unroll
    for (int ni = 0; ni < 2; ++ni) acc[mt][ni] = (floatx4)0.f;

#pragma unroll
  for (int kt = 0; kt < 4; ++kt) {
#pragma unroll
    for (int mt = 0; mt < 8; ++mt) {
      int p = mt * 16 + n16;
      int cpr = (kt * 32 + quad * 8 + 8 * ((p >> 3) & 15)) & 127;
      short8 afr = *(const short8*)&aT[p * 128 + cpr];
      acc[mt][0] = __builtin_amdgcn_mfma_f32_16x16x32_bf16(afr, wf[0][kt], acc[mt][0], 0, 0, 0);
      acc[mt][1] = __builtin_amdgcn_mfma_f32_16x16x32_bf16(afr, wf[1][kt], acc[mt][1], 0, 0, 0);
    }
  }

  // epilogue: lane holds p = mt*16 + quad*4 + r (r=0..3), o = (2w+ni)*16+n16
  float fb0 = fuse_b[(2 * w) * 16 + n16];
  float fb1 = fuse_b[(2 * w + 1) * 16 + n16];
  size_t ob0 = base + (size_t)((2 * w) * 16 + n16) * HW;
  size_t ob1 = base + (size_t)((2 * w + 1) * 16 + n16) * HW;
#pragma unroll
  for (int mt = 0; mt < 8; ++mt) {
    int pq = mt * 16 + quad * 4;
    float4 x0 = *(const float4*)(x + ob0 + pq);
    float4 x1 = *(const float4*)(x + ob1 + pq);
    floatx4 a0 = acc[mt][0], a1 = acc[mt][1];
    float4 r0, r1;
    r0.x = x0.x * fmaf(0.5f, fb0 + a0[0], 0.5f);
    r0.y = x0.y * fmaf(0.5f, fb0 + a0[1], 0.5f);
    r0.z = x0.z * fmaf(0.5f, fb0 + a0[2], 0.5f);
    r0.w = x0.w * fmaf(0.5f, fb0 + a0[3], 0.5f);
    r1.x = x1.x * fmaf(0.5f, fb1 + a1[0], 0.5f);
    r1.y = x1.y * fmaf(0.5f, fb1 + a1[1], 0.5f);
    r1.z = x1.z * fmaf(0.5f, fb1 + a1[2], 0.5f);
    r1.w = x1.w * fmaf(0.5f, fb1 + a1[3], 0.5f);
    *(float4*)(out + ob0 + pq) = r0;
    *(float4*)(out + ob1 + pq) = r1;
  }
}

extern "C" void kernel_launch(void* const* d_in, const int* in_sizes, int n_in,
                              void* d_out, int out_size, void* d_ws, size_t ws_size,
                              hipStream_t stream) {
  const float* x      = (const float*)d_in[0];
  const float* h1w    = (const float*)d_in[1];
  const float* h2w    = (const float*)d_in[2];
  const float* v1w    = (const float*)d_in[3];
  const float* v2w    = (const float*)d_in[4];
  const float* g1w    = (const float*)d_in[5];
  const float* g2w    = (const float*)d_in[6];
  const float* g2b    = (const float*)d_in[7];
  const float* fusew  = (const float*)d_in[8];
  const float* fuseb  = (const float*)d_in[9];
  float* out = (float*)d_out;

  float* sums  = (float*)d_ws;       // sum_h(512), sum_v(512), wgate(8), ctr
  float* wgate = sums + 1024;
  __hip_bfloat16* hbuf = (__hip_bfloat16*)((char*)d_ws + 32768);
  __hip_bfloat16* vbuf = hbuf + (size_t)4 * CCH * HW;

  prep_kernel<<<1, 256, 0, stream>>>(sums);
  conv_kernel<<<12288, 256, 0, stream>>>(x, h1w, h2w, v1w, v2w, g1w, g2w, g2b,
                                         hbuf, vbuf, sums);
  fuse_kernel<<<4 * HGT * 2, 256, 0, stream>>>(x, hbuf, vbuf, fusew, fuseb, wgate, out);
}

// Round 4
// 441.582 us; speedup vs baseline: 5.2687x; 5.2687x over previous
//
#include <hip/hip_runtime.h>
#include <hip/hip_bf16.h>

#define CCH 128
#define HGT 256
#define WID 256
#define HW  65536

typedef __attribute__((ext_vector_type(8))) short short8;
typedef __attribute__((ext_vector_type(4))) float floatx4;

// ws layout:
//   floats [0,512)     sum_h (4*128)
//   floats [512,1024)  sum_v
//   floats [1024,1032) wgate (4*2)
//   byte 32768:        hbuf bf16 (4*128*65536)
//   then               vbuf bf16

__device__ __forceinline__ float bf2f(unsigned short u) {
  return __uint_as_float(((unsigned)u) << 16);
}
__device__ __forceinline__ short f2bfs(float f) {
  return (short)__bfloat16_as_ushort(__float2bfloat16(f));
}

__global__ __launch_bounds__(256) void prep_kernel(float* __restrict__ sums) {
  int t = threadIdx.x;
  for (int i = t; i < 1032; i += 256) sums[i] = 0.f;  // sum_h, sum_v, wgate
}

// Merged directional conv, 12288 blocks (round-2 version, NO fence/gate —
// the round-3 per-block __threadfence cost 165 ns x 12288 = 1.9 ms).
__global__ __launch_bounds__(256) void conv_kernel(
    const float* __restrict__ x,
    const float* __restrict__ h1w, const float* __restrict__ h2w,
    const float* __restrict__ v1w, const float* __restrict__ v2w,
    __hip_bfloat16* __restrict__ hbuf, __hip_bfloat16* __restrict__ vbuf,
    float* __restrict__ sum_h, float* __restrict__ sum_v) {
  int d = blockIdx.x;
  int l = (d & 7) * 1536 + (d >> 3);   // bijective XCD chunking: 12288 % 8 == 0
  int t = threadIdx.x;
  float acc = 0.f;
  int bcg;
  float* sums;
  if (l < 8192) {
    // ---- horizontal: block = (b,c, 16-row tile); thread = 16 consecutive px
    int bc = l >> 4;
    int c = bc & (CCH - 1);
    int row = (l & 15) * 16 + (t >> 4);
    int p0 = (t & 15) * 16;
    const float* xr = x + (size_t)bc * HW + (size_t)row * WID;
    float w1[5], w2[7];
#pragma unroll
    for (int i = 0; i < 5; ++i) w1[i] = h1w[c * 5 + i];
#pragma unroll
    for (int j = 0; j < 7; ++j) w2[j] = h2w[c * 7 + j];
    float xv[40];
#pragma unroll
    for (int k = 0; k < 10; ++k) {
      int col = p0 - 12 + 4 * k;
      float4 v = make_float4(0.f, 0.f, 0.f, 0.f);
      if (col >= 0 && col < WID) v = *(const float4*)(xr + col);
      xv[4 * k] = v.x; xv[4 * k + 1] = v.y; xv[4 * k + 2] = v.z; xv[4 * k + 3] = v.w;
    }
    float s1[34];
#pragma unroll
    for (int m = 0; m < 34; ++m) {
      int q = p0 - 9 + m;
      float s = 0.f;
#pragma unroll
      for (int i = 0; i < 5; ++i) s = fmaf(xv[m + 1 + i], w1[i], s);
      s1[m] = ((unsigned)q < (unsigned)WID) ? s : 0.f;
    }
    short8 st0, st1;
#pragma unroll
    for (int u = 0; u < 16; ++u) {
      float s = 0.f;
#pragma unroll
      for (int j = 0; j < 7; ++j) s = fmaf(s1[u + 3 * j], w2[j], s);
      if (u < 8) st0[u] = f2bfs(s); else st1[u - 8] = f2bfs(s);
      acc += s;
    }
    unsigned short* hp = (unsigned short*)hbuf + (size_t)bc * HW + (size_t)row * WID + p0;
    *(short8*)hp = st0;
    *(short8*)(hp + 8) = st1;
    bcg = bc; sums = sum_h;
  } else {
    // ---- vertical: block = (b,c, 32-row tile); thread = one column, 32 y's
    int lb = l - 8192;
    int bc = lb >> 3;
    int c = bc & (CCH - 1);
    int y0 = (lb & 7) * 32;
    const float* xc = x + (size_t)bc * HW + t;
    float w1[5], w2[7];
#pragma unroll
    for (int i = 0; i < 5; ++i) w1[i] = v1w[c * 5 + i];
#pragma unroll
    for (int j = 0; j < 7; ++j) w2[j] = v2w[c * 7 + j];
    float xv[54];
#pragma unroll
    for (int m = 0; m < 54; ++m) {
      int yy = y0 - 11 + m;
      xv[m] = ((unsigned)yy < (unsigned)HGT) ? xc[(size_t)yy * WID] : 0.f;
    }
    float s1[50];
#pragma unroll
    for (int m = 0; m < 50; ++m) {
      int q = y0 - 9 + m;
      float s = 0.f;
#pragma unroll
      for (int i = 0; i < 5; ++i) s = fmaf(xv[m + i], w1[i], s);
      s1[m] = ((unsigned)q < (unsigned)HGT) ? s : 0.f;
    }
    unsigned short* vp = (unsigned short*)vbuf + (size_t)bc * HW + t;
#pragma unroll
    for (int u = 0; u < 32; ++u) {
      float s = 0.f;
#pragma unroll
      for (int j = 0; j < 7; ++j) s = fmaf(s1[u + 3 * j], w2[j], s);
      vp[(size_t)(y0 + u) * WID] = (unsigned short)f2bfs(s);
      acc += s;
    }
    bcg = bc; sums = sum_v;
  }
#pragma unroll
  for (int off = 32; off > 0; off >>= 1) acc += __shfl_down(acc, off);
  if ((t & 63) == 0) atomicAdd(&sums[bcg], acc);
}

// single block: pooled -> g1 -> SiLU -> g2 -> softmax
__global__ __launch_bounds__(128) void gate_kernel(
    const float* __restrict__ sum_h, const float* __restrict__ sum_v,
    const float* __restrict__ g1w, const float* __restrict__ g2w,
    const float* __restrict__ g2b, float* __restrict__ wgate) {
  int t = threadIdx.x;
  __shared__ float gs[4][32];
  int b = t >> 5, r = t & 31;
  {
    float acc = 0.f;
    const float inv = 1.f / 65536.f;
    for (int k = 0; k < 128; ++k)
      acc = fmaf(sum_h[b * 128 + k] * inv, g1w[r * 256 + k], acc);
    for (int k = 0; k < 128; ++k)
      acc = fmaf(sum_v[b * 128 + k] * inv, g1w[r * 256 + 128 + k], acc);
    float sig = 1.f / (1.f + expf(-acc));
    gs[b][r] = acc * sig;
  }
  __syncthreads();
  if (t < 4) {
    float t0 = g2b[0], t1 = g2b[1];
    for (int rr = 0; rr < 32; ++rr) {
      t0 = fmaf(gs[t][rr], g2w[rr], t0);
      t1 = fmaf(gs[t][rr], g2w[32 + rr], t1);
    }
    float mx = fmaxf(t0, t1);
    float e0 = expf(t0 - mx), e1 = expf(t1 - mx);
    float inv = 1.f / (e0 + e1);
    wgate[t * 2 + 0] = e0 * inv;
    wgate[t * 2 + 1] = e1 * inv;
  }
}

// MFMA fuse: one block per (b, y, half) = 128 o x 128 p, K = 128 c.
// Operand-swapped MFMA — D[p][o] = mfma(aT_frag, W_frag, acc): each lane's 4
// acc regs are 4 CONSECUTIVE PIXELS at fixed o, so the epilogue is 16 float4
// x-loads + 16 float4 stores instead of 64 scalar loads + 64 scalar stores.
__global__ __launch_bounds__(256, 4) void fuse_kernel(
    const float* __restrict__ x, const __hip_bfloat16* __restrict__ hbuf,
    const __hip_bfloat16* __restrict__ vbuf, const float* __restrict__ fuse_w,
    const float* __restrict__ fuse_b, const float* __restrict__ wgate,
    float* __restrict__ out) {
  __shared__ unsigned short aT[128 * 128];  // [p][c'] bf16, 32 KB
  int bid = blockIdx.x;        // (b*256 + y)*2 + half
  int half = bid & 1;
  int y = (bid >> 1) & 255;
  int b = bid >> 9;
  int t = threadIdx.x;
  int w = t >> 6, lane = t & 63;
  int quad = lane >> 4, n16 = lane & 15;
  float wh = wgate[b * 2], wv = wgate[b * 2 + 1];

  // W fragments (B-operand): wave w covers o in [32w, 32w+32)
  short8 wf[2][4];
#pragma unroll
  for (int ni = 0; ni < 2; ++ni) {
    int o = (2 * w + ni) * 16 + n16;
#pragma unroll
    for (int kt = 0; kt < 4; ++kt) {
      const float* wp = fuse_w + o * 128 + kt * 32 + quad * 8;
      float4 f0 = *(const float4*)wp;
      float4 f1 = *(const float4*)(wp + 4);
      short8 s;
      s[0] = f2bfs(f0.x); s[1] = f2bfs(f0.y); s[2] = f2bfs(f0.z); s[3] = f2bfs(f0.w);
      s[4] = f2bfs(f1.x); s[5] = f2bfs(f1.y); s[6] = f2bfs(f1.z); s[7] = f2bfs(f1.w);
      wf[ni][kt] = s;
    }
  }

  // stage a = wh*h + wv*v into aT[p][c'], c' = (c + 8*((p>>3)&15)) & 127
  size_t base = (size_t)(b * CCH) * HW + (size_t)y * WID + half * 128;
  const unsigned short* hb = (const unsigned short*)hbuf;
  const unsigned short* vb = (const unsigned short*)vbuf;
  int cth = t >> 4;
  int p0 = (t & 15) * 8;
  int swz = 8 * (t & 15);      // 8*((p>>3)&15), constant over the thread's 8 p
#pragma unroll
  for (int cpass = 0; cpass < 8; ++cpass) {
    int c = cpass * 16 + cth;
    size_t gi = base + (size_t)c * HW + p0;
    short8 h8 = *(const short8*)(hb + gi);
    short8 v8 = *(const short8*)(vb + gi);
    int cpr = (c + swz) & 127;
    float a0 = fmaf(wh, bf2f((unsigned short)h8[0]), wv * bf2f((unsigned short)v8[0]));
    float a1 = fmaf(wh, bf2f((unsigned short)h8[1]), wv * bf2f((unsigned short)v8[1]));
    float a2 = fmaf(wh, bf2f((unsigned short)h8[2]), wv * bf2f((unsigned short)v8[2]));
    float a3 = fmaf(wh, bf2f((unsigned short)h8[3]), wv * bf2f((unsigned short)v8[3]));
    float a4 = fmaf(wh, bf2f((unsigned short)h8[4]), wv * bf2f((unsigned short)v8[4]));
    float a5 = fmaf(wh, bf2f((unsigned short)h8[5]), wv * bf2f((unsigned short)v8[5]));
    float a6 = fmaf(wh, bf2f((unsigned short)h8[6]), wv * bf2f((unsigned short)v8[6]));
    float a7 = fmaf(wh, bf2f((unsigned short)h8[7]), wv * bf2f((unsigned short)v8[7]));
    aT[(p0 + 0) * 128 + cpr] = (unsigned short)f2bfs(a0);
    aT[(p0 + 1) * 128 + cpr] = (unsigned short)f2bfs(a1);
    aT[(p0 + 2) * 128 + cpr] = (unsigned short)f2bfs(a2);
    aT[(p0 + 3) * 128 + cpr] = (unsigned short)f2bfs(a3);
    aT[(p0 + 4) * 128 + cpr] = (unsigned short)f2bfs(a4);
    aT[(p0 + 5) * 128 + cpr] = (unsigned short)f2bfs(a5);
    aT[(p0 + 6) * 128 + cpr] = (unsigned short)f2bfs(a6);
    aT[(p0 + 7) * 128 + cpr] = (unsigned short)f2bfs(a7);
  }
  __syncthreads();

  // MFMA: acc[mt][ni] = D[p-tile mt][o-tile 2w+ni]
  floatx4 acc[8][2];
#pragma unroll
  for (int mt = 0; mt < 8; ++mt)
#pragma unroll
    for (int ni = 0; ni < 2; ++ni) acc[mt][ni] = (floatx4)0.f;

#pragma unroll
  for (int kt = 0; kt < 4; ++kt) {
#pragma unroll
    for (int mt = 0; mt < 8; ++mt) {
      int p = mt * 16 + n16;
      int cpr = (kt * 32 + quad * 8 + 8 * ((p >> 3) & 15)) & 127;
      short8 afr = *(const short8*)&aT[p * 128 + cpr];
      acc[mt][0] = __builtin_amdgcn_mfma_f32_16x16x32_bf16(afr, wf[0][kt], acc[mt][0], 0, 0, 0);
      acc[mt][1] = __builtin_amdgcn_mfma_f32_16x16x32_bf16(afr, wf[1][kt], acc[mt][1], 0, 0, 0);
    }
  }

  // epilogue: lane holds p = mt*16 + quad*4 + r (r=0..3), o = (2w+ni)*16+n16
  float fb0 = fuse_b[(2 * w) * 16 + n16];
  float fb1 = fuse_b[(2 * w + 1) * 16 + n16];
  size_t ob0 = base + (size_t)((2 * w) * 16 + n16) * HW;
  size_t ob1 = base + (size_t)((2 * w + 1) * 16 + n16) * HW;
#pragma unroll
  for (int mt = 0; mt < 8; ++mt) {
    int pq = mt * 16 + quad * 4;
    float4 x0 = *(const float4*)(x + ob0 + pq);
    float4 x1 = *(const float4*)(x + ob1 + pq);
    floatx4 a0 = acc[mt][0], a1 = acc[mt][1];
    float4 r0, r1;
    r0.x = x0.x * fmaf(0.5f, fb0 + a0[0], 0.5f);
    r0.y = x0.y * fmaf(0.5f, fb0 + a0[1], 0.5f);
    r0.z = x0.z * fmaf(0.5f, fb0 + a0[2], 0.5f);
    r0.w = x0.w * fmaf(0.5f, fb0 + a0[3], 0.5f);
    r1.x = x1.x * fmaf(0.5f, fb1 + a1[0], 0.5f);
    r1.y = x1.y * fmaf(0.5f, fb1 + a1[1], 0.5f);
    r1.z = x1.z * fmaf(0.5f, fb1 + a1[2], 0.5f);
    r1.w = x1.w * fmaf(0.5f, fb1 + a1[3], 0.5f);
    *(float4*)(out + ob0 + pq) = r0;
    *(float4*)(out + ob1 + pq) = r1;
  }
}

extern "C" void kernel_launch(void* const* d_in, const int* in_sizes, int n_in,
                              void* d_out, int out_size, void* d_ws, size_t ws_size,
                              hipStream_t stream) {
  const float* x      = (const float*)d_in[0];
  const float* h1w    = (const float*)d_in[1];
  const float* h2w    = (const float*)d_in[2];
  const float* v1w    = (const float*)d_in[3];
  const float* v2w    = (const float*)d_in[4];
  const float* g1w    = (const float*)d_in[5];
  const float* g2w    = (const float*)d_in[6];
  const float* g2b    = (const float*)d_in[7];
  const float* fusew  = (const float*)d_in[8];
  const float* fuseb  = (const float*)d_in[9];
  float* out = (float*)d_out;

  float* sums  = (float*)d_ws;       // sum_h(512), sum_v(512), wgate(8)
  float* sum_h = sums;
  float* sum_v = sums + 512;
  float* wgate = sums + 1024;
  __hip_bfloat16* hbuf = (__hip_bfloat16*)((char*)d_ws + 32768);
  __hip_bfloat16* vbuf = hbuf + (size_t)4 * CCH * HW;

  prep_kernel<<<1, 256, 0, stream>>>(sums);
  conv_kernel<<<12288, 256, 0, stream>>>(x, h1w, h2w, v1w, v2w, hbuf, vbuf, sum_h, sum_v);
  gate_kernel<<<1, 128, 0, stream>>>(sum_h, sum_v, g1w, g2w, g2b, wgate);
  fuse_kernel<<<4 * HGT * 2, 256, 0, stream>>>(x, hbuf, vbuf, fusew, fuseb, wgate, out);
}

// Round 5
// 386.756 us; speedup vs baseline: 6.0156x; 1.1418x over previous
//
#include <hip/hip_runtime.h>
#include <hip/hip_bf16.h>

#define CCH 128
#define HGT 256
#define WID 256
#define HW  65536

typedef __attribute__((ext_vector_type(8))) short short8;
typedef __attribute__((ext_vector_type(4))) float floatx4;

// ws layout:
//   floats [0,512)     sum_h (4*128)
//   floats [512,1024)  sum_v
//   floats [1024,1032) wgate (4*2)
//   byte 32768:        hbuf bf16 (4*128*65536)
//   then               vbuf bf16

__device__ __forceinline__ float bf2f(unsigned short u) {
  return __uint_as_float(((unsigned)u) << 16);
}
__device__ __forceinline__ short f2bfs(float f) {
  return (short)__bfloat16_as_ushort(__float2bfloat16(f));
}

__global__ __launch_bounds__(256) void prep_kernel(float* __restrict__ sums) {
  int t = threadIdx.x;
  for (int i = t; i < 1032; i += 256) sums[i] = 0.f;  // sum_h, sum_v, wgate
}

// Merged directional conv, 12288 blocks (round-2 version, NO fence/gate —
// the round-3 per-block __threadfence cost 165 ns x 12288 = 1.9 ms).
__global__ __launch_bounds__(256) void conv_kernel(
    const float* __restrict__ x,
    const float* __restrict__ h1w, const float* __restrict__ h2w,
    const float* __restrict__ v1w, const float* __restrict__ v2w,
    __hip_bfloat16* __restrict__ hbuf, __hip_bfloat16* __restrict__ vbuf,
    float* __restrict__ sum_h, float* __restrict__ sum_v) {
  int d = blockIdx.x;
  int l = (d & 7) * 1536 + (d >> 3);   // bijective XCD chunking: 12288 % 8 == 0
  int t = threadIdx.x;
  float acc = 0.f;
  int bcg;
  float* sums;
  if (l < 8192) {
    // ---- horizontal: block = (b,c, 16-row tile); thread = 16 consecutive px
    int bc = l >> 4;
    int c = bc & (CCH - 1);
    int row = (l & 15) * 16 + (t >> 4);
    int p0 = (t & 15) * 16;
    const float* xr = x + (size_t)bc * HW + (size_t)row * WID;
    float w1[5], w2[7];
#pragma unroll
    for (int i = 0; i < 5; ++i) w1[i] = h1w[c * 5 + i];
#pragma unroll
    for (int j = 0; j < 7; ++j) w2[j] = h2w[c * 7 + j];
    float xv[40];
#pragma unroll
    for (int k = 0; k < 10; ++k) {
      int col = p0 - 12 + 4 * k;
      float4 v = make_float4(0.f, 0.f, 0.f, 0.f);
      if (col >= 0 && col < WID) v = *(const float4*)(xr + col);
      xv[4 * k] = v.x; xv[4 * k + 1] = v.y; xv[4 * k + 2] = v.z; xv[4 * k + 3] = v.w;
    }
    float s1[34];
#pragma unroll
    for (int m = 0; m < 34; ++m) {
      int q = p0 - 9 + m;
      float s = 0.f;
#pragma unroll
      for (int i = 0; i < 5; ++i) s = fmaf(xv[m + 1 + i], w1[i], s);
      s1[m] = ((unsigned)q < (unsigned)WID) ? s : 0.f;
    }
    short8 st0, st1;
#pragma unroll
    for (int u = 0; u < 16; ++u) {
      float s = 0.f;
#pragma unroll
      for (int j = 0; j < 7; ++j) s = fmaf(s1[u + 3 * j], w2[j], s);
      if (u < 8) st0[u] = f2bfs(s); else st1[u - 8] = f2bfs(s);
      acc += s;
    }
    unsigned short* hp = (unsigned short*)hbuf + (size_t)bc * HW + (size_t)row * WID + p0;
    *(short8*)hp = st0;
    *(short8*)(hp + 8) = st1;
    bcg = bc; sums = sum_h;
  } else {
    // ---- vertical: block = (b,c, 32-row tile); thread = one column, 32 y's
    int lb = l - 8192;
    int bc = lb >> 3;
    int c = bc & (CCH - 1);
    int y0 = (lb & 7) * 32;
    const float* xc = x + (size_t)bc * HW + t;
    float w1[5], w2[7];
#pragma unroll
    for (int i = 0; i < 5; ++i) w1[i] = v1w[c * 5 + i];
#pragma unroll
    for (int j = 0; j < 7; ++j) w2[j] = v2w[c * 7 + j];
    float xv[54];
#pragma unroll
    for (int m = 0; m < 54; ++m) {
      int yy = y0 - 11 + m;
      xv[m] = ((unsigned)yy < (unsigned)HGT) ? xc[(size_t)yy * WID] : 0.f;
    }
    float s1[50];
#pragma unroll
    for (int m = 0; m < 50; ++m) {
      int q = y0 - 9 + m;
      float s = 0.f;
#pragma unroll
      for (int i = 0; i < 5; ++i) s = fmaf(xv[m + i], w1[i], s);
      s1[m] = ((unsigned)q < (unsigned)HGT) ? s : 0.f;
    }
    unsigned short* vp = (unsigned short*)vbuf + (size_t)bc * HW + t;
#pragma unroll
    for (int u = 0; u < 32; ++u) {
      float s = 0.f;
#pragma unroll
      for (int j = 0; j < 7; ++j) s = fmaf(s1[u + 3 * j], w2[j], s);
      vp[(size_t)(y0 + u) * WID] = (unsigned short)f2bfs(s);
      acc += s;
    }
    bcg = bc; sums = sum_v;
  }
#pragma unroll
  for (int off = 32; off > 0; off >>= 1) acc += __shfl_down(acc, off);
  if ((t & 63) == 0) atomicAdd(&sums[bcg], acc);
}

// single block: pooled -> g1 -> SiLU -> g2 -> softmax
__global__ __launch_bounds__(128) void gate_kernel(
    const float* __restrict__ sum_h, const float* __restrict__ sum_v,
    const float* __restrict__ g1w, const float* __restrict__ g2w,
    const float* __restrict__ g2b, float* __restrict__ wgate) {
  int t = threadIdx.x;
  __shared__ float gs[4][32];
  int b = t >> 5, r = t & 31;
  {
    float acc = 0.f;
    const float inv = 1.f / 65536.f;
    for (int k = 0; k < 128; ++k)
      acc = fmaf(sum_h[b * 128 + k] * inv, g1w[r * 256 + k], acc);
    for (int k = 0; k < 128; ++k)
      acc = fmaf(sum_v[b * 128 + k] * inv, g1w[r * 256 + 128 + k], acc);
    float sig = 1.f / (1.f + expf(-acc));
    gs[b][r] = acc * sig;
  }
  __syncthreads();
  if (t < 4) {
    float t0 = g2b[0], t1 = g2b[1];
    for (int rr = 0; rr < 32; ++rr) {
      t0 = fmaf(gs[t][rr], g2w[rr], t0);
      t1 = fmaf(gs[t][rr], g2w[32 + rr], t1);
    }
    float mx = fmaxf(t0, t1);
    float e0 = expf(t0 - mx), e1 = expf(t1 - mx);
    float inv = 1.f / (e0 + e1);
    wgate[t * 2 + 0] = e0 * inv;
    wgate[t * 2 + 1] = e1 * inv;
  }
}

// MFMA fuse: one block per (b, y, half) = 128 o x 128 p, K = 128 c.
// v5 changes vs v4 (single-kernel focus):
//  (1) all 16 staging loads hoisted into hv[16] BEFORE any combine/ds_write
//      (16-deep MLP; ~900-cycle HBM latency paid once, not 4-8 times)
//  (2) wf (W fragments) loaded AFTER staging stores — frees 32 VGPRs for (1),
//      loads overlap the __syncthreads wait
//  (3) granule-XOR LDS swizzle: element (p,c) at aT[p*128 + g'*8 + (c&7)],
//      g' = (c>>3) ^ (p&15) ^ (p>>4). Reads: g' bijective over the 16 n16
//      lanes -> 2 lanes/bank (free). Writes: p>>4 term keeps ~4-way spread.
__global__ __launch_bounds__(256, 4) void fuse_kernel(
    const float* __restrict__ x, const __hip_bfloat16* __restrict__ hbuf,
    const __hip_bfloat16* __restrict__ vbuf, const float* __restrict__ fuse_w,
    const float* __restrict__ fuse_b, const float* __restrict__ wgate,
    float* __restrict__ out) {
  __shared__ unsigned short aT[128 * 128];  // swizzled [p][c'] bf16, 32 KB
  int bid = blockIdx.x;        // (b*256 + y)*2 + half
  int half = bid & 1;
  int y = (bid >> 1) & 255;
  int b = bid >> 9;
  int t = threadIdx.x;
  int w = t >> 6, lane = t & 63;
  int quad = lane >> 4, n16 = lane & 15;
  float wh = wgate[b * 2], wv = wgate[b * 2 + 1];

  size_t base = (size_t)(b * CCH) * HW + (size_t)y * WID + half * 128;
  const unsigned short* hb = (const unsigned short*)hbuf;
  const unsigned short* vb = (const unsigned short*)vbuf;
  int cth = t >> 4;
  int p0 = (t & 15) * 8;

  // (1) issue ALL staging loads first
  short8 hv[16];
#pragma unroll
  for (int cpass = 0; cpass < 8; ++cpass) {
    int c = cpass * 16 + cth;
    size_t gi = base + (size_t)c * HW + p0;
    hv[2 * cpass]     = *(const short8*)(hb + gi);
    hv[2 * cpass + 1] = *(const short8*)(vb + gi);
  }
  // combine + transposed swizzled ds_write
#pragma unroll
  for (int cpass = 0; cpass < 8; ++cpass) {
    int c = cpass * 16 + cth;
    int g = c >> 3, c7 = c & 7;
#pragma unroll
    for (int e = 0; e < 8; ++e) {
      float a = fmaf(wh, bf2f((unsigned short)hv[2 * cpass][e]),
                     wv * bf2f((unsigned short)hv[2 * cpass + 1][e]));
      int p = p0 + e;
      int gp = g ^ (p & 15) ^ (p >> 4);
      aT[p * 128 + gp * 8 + c7] = (unsigned short)f2bfs(a);
    }
  }

  // (2) W fragments (B-operand), loaded while waiting for the barrier
  short8 wf[2][4];
#pragma unroll
  for (int ni = 0; ni < 2; ++ni) {
    int o = (2 * w + ni) * 16 + n16;
#pragma unroll
    for (int kt = 0; kt < 4; ++kt) {
      const float* wp = fuse_w + o * 128 + kt * 32 + quad * 8;
      float4 f0 = *(const float4*)wp;
      float4 f1 = *(const float4*)(wp + 4);
      short8 s;
      s[0] = f2bfs(f0.x); s[1] = f2bfs(f0.y); s[2] = f2bfs(f0.z); s[3] = f2bfs(f0.w);
      s[4] = f2bfs(f1.x); s[5] = f2bfs(f1.y); s[6] = f2bfs(f1.z); s[7] = f2bfs(f1.w);
      wf[ni][kt] = s;
    }
  }
  __syncthreads();

  // MFMA: acc[mt][ni] = D[p-tile mt][o-tile 2w+ni]
  floatx4 acc[8][2];
#pragma unroll
  for (int mt = 0; mt < 8; ++mt)
#pragma unroll
    for (int ni = 0; ni < 2; ++ni) acc[mt][ni] = (floatx4)0.f;

#pragma unroll
  for (int kt = 0; kt < 4; ++kt) {
#pragma unroll
    for (int mt = 0; mt < 8; ++mt) {
      int p = mt * 16 + n16;
      int gp = (4 * kt + quad) ^ (p & 15) ^ (p >> 4);
      short8 afr = *(const short8*)&aT[p * 128 + gp * 8];
      acc[mt][0] = __builtin_amdgcn_mfma_f32_16x16x32_bf16(afr, wf[0][kt], acc[mt][0], 0, 0, 0);
      acc[mt][1] = __builtin_amdgcn_mfma_f32_16x16x32_bf16(afr, wf[1][kt], acc[mt][1], 0, 0, 0);
    }
  }

  // epilogue: lane holds p = mt*16 + quad*4 + r (r=0..3), o = (2w+ni)*16+n16
  float fb0 = fuse_b[(2 * w) * 16 + n16];
  float fb1 = fuse_b[(2 * w + 1) * 16 + n16];
  size_t ob0 = base + (size_t)((2 * w) * 16 + n16) * HW;
  size_t ob1 = base + (size_t)((2 * w + 1) * 16 + n16) * HW;
#pragma unroll
  for (int mt = 0; mt < 8; ++mt) {
    int pq = mt * 16 + quad * 4;
    float4 x0 = *(const float4*)(x + ob0 + pq);
    float4 x1 = *(const float4*)(x + ob1 + pq);
    floatx4 a0 = acc[mt][0], a1 = acc[mt][1];
    float4 r0, r1;
    r0.x = x0.x * fmaf(0.5f, fb0 + a0[0], 0.5f);
    r0.y = x0.y * fmaf(0.5f, fb0 + a0[1], 0.5f);
    r0.z = x0.z * fmaf(0.5f, fb0 + a0[2], 0.5f);
    r0.w = x0.w * fmaf(0.5f, fb0 + a0[3], 0.5f);
    r1.x = x1.x * fmaf(0.5f, fb1 + a1[0], 0.5f);
    r1.y = x1.y * fmaf(0.5f, fb1 + a1[1], 0.5f);
    r1.z = x1.z * fmaf(0.5f, fb1 + a1[2], 0.5f);
    r1.w = x1.w * fmaf(0.5f, fb1 + a1[3], 0.5f);
    *(float4*)(out + ob0 + pq) = r0;
    *(float4*)(out + ob1 + pq) = r1;
  }
}

extern "C" void kernel_launch(void* const* d_in, const int* in_sizes, int n_in,
                              void* d_out, int out_size, void* d_ws, size_t ws_size,
                              hipStream_t stream) {
  const float* x      = (const float*)d_in[0];
  const float* h1w    = (const float*)d_in[1];
  const float* h2w    = (const float*)d_in[2];
  const float* v1w    = (const float*)d_in[3];
  const float* v2w    = (const float*)d_in[4];
  const float* g1w    = (const float*)d_in[5];
  const float* g2w    = (const float*)d_in[6];
  const float* g2b    = (const float*)d_in[7];
  const float* fusew  = (const float*)d_in[8];
  const float* fuseb  = (const float*)d_in[9];
  float* out = (float*)d_out;

  float* sums  = (float*)d_ws;       // sum_h(512), sum_v(512), wgate(8)
  float* sum_h = sums;
  float* sum_v = sums + 512;
  float* wgate = sums + 1024;
  __hip_bfloat16* hbuf = (__hip_bfloat16*)((char*)d_ws + 32768);
  __hip_bfloat16* vbuf = hbuf + (size_t)4 * CCH * HW;

  prep_kernel<<<1, 256, 0, stream>>>(sums);
  conv_kernel<<<12288, 256, 0, stream>>>(x, h1w, h2w, v1w, v2w, hbuf, vbuf, sum_h, sum_v);
  gate_kernel<<<1, 128, 0, stream>>>(sum_h, sum_v, g1w, g2w, g2b, wgate);
  fuse_kernel<<<4 * HGT * 2, 256, 0, stream>>>(x, hbuf, vbuf, fusew, fuseb, wgate, out);
}